// Round 4
// baseline (1189.200 us; speedup 1.0000x reference)
//
#include <hip/hip_runtime.h>

#define N_VEC   32768      // 32*1024
#define K_CODES 4096
#define D_DIM   64
#define NELEM   2097152    // N_VEC * D_DIM

// ---- output layout (floats, concatenated in reference return order) ----
#define OUT0_OFF 0           // quantized_st  (2097152)
#define OUT1_OFF 2097152     // loss          (1)
#define OUT2_OFF 2097153     // indices       (32768)
#define OUT3_OFF 2129921     // new_weight    (262144)
#define OUT4_OFF 2392065     // ema_cs        (4096)
#define OUT5_OFF 2396161     // ema_es        (262144)

// ---- ws layout (byte offsets, 8-aligned) ----
#define WS_BNORM   0            // float[4096]       (16384 B)  np-exact ||w_k||^2
#define WS_COUNTS  16384        // int[4096]         (16384 B)
#define WS_SUMS    32768        // float[4096*64]    (1048576 B)
#define WS_LPART   1081344      // double[8192]      (65536 B)
#define WS_CSPART  1146880      // double[16]        (128 B)

// numpy pairwise_sum base case (n=64): 8 accumulators strided by 8,
// sequential adds, fixed combine tree. sq[] must be PRE-ROUNDED squares.
__device__ __forceinline__ float np_pairwise64(const float* sq) {
    float r0 = sq[0], r1 = sq[1], r2 = sq[2], r3 = sq[3];
    float r4 = sq[4], r5 = sq[5], r6 = sq[6], r7 = sq[7];
#pragma unroll
    for (int b = 8; b < 64; b += 8) {
        r0 = __fadd_rn(r0, sq[b + 0]); r1 = __fadd_rn(r1, sq[b + 1]);
        r2 = __fadd_rn(r2, sq[b + 2]); r3 = __fadd_rn(r3, sq[b + 3]);
        r4 = __fadd_rn(r4, sq[b + 4]); r5 = __fadd_rn(r5, sq[b + 5]);
        r6 = __fadd_rn(r6, sq[b + 6]); r7 = __fadd_rn(r7, sq[b + 7]);
    }
    return __fadd_rn(__fadd_rn(__fadd_rn(r0, r1), __fadd_rn(r2, r3)),
                     __fadd_rn(__fadd_rn(r4, r5), __fadd_rn(r6, r7)));
}

// -------- B_k = np.sum(w_k*w_k) with numpy fp32 semantics ----------------
__global__ void k_bnorm(const float* __restrict__ w, float* __restrict__ bn) {
    int k = blockIdx.x * 256 + threadIdx.x;
    const float* wr = w + k * D_DIM;
    float sq[64];
#pragma unroll
    for (int i = 0; i < 64; ++i) { float v = wr[i]; sq[i] = __fmul_rn(v, v); }
    bn[k] = np_pairwise64(sq);
}

// -------- scorer: bit-replicate np fp32 distances, argmin first-index ----
// Block = 256 threads = 4 waves. Wave wid owns k-slice [wid*1024,(wid+1)*1024);
// each of its 64 lanes owns row n = blockIdx*64 + lane. All lanes of a wave
// read the SAME w addresses (wave-uniform k) -> single coalesced fetch.
// x is held in 16 named float4 VGPRs; __launch_bounds__(256,2) stops the
// compiler from sinking the x loads back into the loop (R3: VGPR=36 disaster).
// d_nk = fl( fl(A_n + B_k) - 2*C_nk ), C_nk = ascending-d fp32 FMA chain.
#define CH4(acc, xc, wc)                                \
    acc = __fmaf_rn((xc).x, (wc).x, acc);               \
    acc = __fmaf_rn((xc).y, (wc).y, acc);               \
    acc = __fmaf_rn((xc).z, (wc).z, acc);               \
    acc = __fmaf_rn((xc).w, (wc).w, acc);

#define STEP(c, xc)                                     \
    { float4 u0 = w0[c], u1 = w1[c], u2 = w2[c], u3 = w3[c]; \
      CH4(a0, xc, u0); CH4(a1, xc, u1);                 \
      CH4(a2, xc, u2); CH4(a3, xc, u3); }

#define SQ4(j, xc)                                      \
    sq[4*(j)+0] = __fmul_rn((xc).x, (xc).x);            \
    sq[4*(j)+1] = __fmul_rn((xc).y, (xc).y);            \
    sq[4*(j)+2] = __fmul_rn((xc).z, (xc).z);            \
    sq[4*(j)+3] = __fmul_rn((xc).w, (xc).w);

__global__ __launch_bounds__(256, 2) void k_score(
    const float* __restrict__ x, const float* __restrict__ w,
    const float* __restrict__ bn, float* __restrict__ out_idx) {
    const int lane = threadIdx.x & 63;
    const int wid  = threadIdx.x >> 6;          // 0..3 = k-slice
    const int n    = blockIdx.x * 64 + lane;
    const int k0   = wid * 1024;

    const float4* xr = (const float4*)(x + (size_t)n * D_DIM);
    float4 x0 = xr[0],  x1 = xr[1],  x2 = xr[2],  x3 = xr[3];
    float4 x4 = xr[4],  x5 = xr[5],  x6 = xr[6],  x7 = xr[7];
    float4 x8 = xr[8],  x9 = xr[9],  x10 = xr[10], x11 = xr[11];
    float4 x12 = xr[12], x13 = xr[13], x14 = xr[14], x15 = xr[15];

    // A_n: numpy-exact sum of pre-rounded squares
    float A;
    {
        float sq[64];
        SQ4(0, x0);  SQ4(1, x1);  SQ4(2, x2);  SQ4(3, x3);
        SQ4(4, x4);  SQ4(5, x5);  SQ4(6, x6);  SQ4(7, x7);
        SQ4(8, x8);  SQ4(9, x9);  SQ4(10, x10); SQ4(11, x11);
        SQ4(12, x12); SQ4(13, x13); SQ4(14, x14); SQ4(15, x15);
        A = np_pairwise64(sq);
    }

    float bestd = 3.4e38f;
    int   besti = k0;
    for (int kb = k0; kb < k0 + 1024; kb += 4) {
        const float4* w0 = (const float4*)(w + (size_t)(kb + 0) * D_DIM);
        const float4* w1 = (const float4*)(w + (size_t)(kb + 1) * D_DIM);
        const float4* w2 = (const float4*)(w + (size_t)(kb + 2) * D_DIM);
        const float4* w3 = (const float4*)(w + (size_t)(kb + 3) * D_DIM);
        float a0 = 0.f, a1 = 0.f, a2 = 0.f, a3 = 0.f;
        STEP(0, x0);  STEP(1, x1);  STEP(2, x2);  STEP(3, x3);
        STEP(4, x4);  STEP(5, x5);  STEP(6, x6);  STEP(7, x7);
        STEP(8, x8);  STEP(9, x9);  STEP(10, x10); STEP(11, x11);
        STEP(12, x12); STEP(13, x13); STEP(14, x14); STEP(15, x15);
        float d0 = __fsub_rn(__fadd_rn(A, bn[kb + 0]), __fmul_rn(2.0f, a0));
        float d1 = __fsub_rn(__fadd_rn(A, bn[kb + 1]), __fmul_rn(2.0f, a1));
        float d2 = __fsub_rn(__fadd_rn(A, bn[kb + 2]), __fmul_rn(2.0f, a2));
        float d3 = __fsub_rn(__fadd_rn(A, bn[kb + 3]), __fmul_rn(2.0f, a3));
        if (d0 < bestd) { bestd = d0; besti = kb + 0; }   // ascending k:
        if (d1 < bestd) { bestd = d1; besti = kb + 1; }   // strict < keeps
        if (d2 < bestd) { bestd = d2; besti = kb + 2; }   // first min, like
        if (d3 < bestd) { bestd = d3; besti = kb + 3; }   // np.argmin
    }

    // merge the 4 k-slices (ascending slice order preserves first-min)
    __shared__ float sbd[4][64];
    __shared__ int   sbi[4][64];
    sbd[wid][lane] = bestd;
    sbi[wid][lane] = besti;
    __syncthreads();
    if (threadIdx.x < 64) {
        float bd = sbd[0][lane];
        int   bi = sbi[0][lane];
#pragma unroll
        for (int s = 1; s < 4; ++s) {
            float od = sbd[s][lane];
            int   oi = sbi[s][lane];
            if (od < bd) { bd = od; bi = oi; }   // strict <: lower slice wins ties
        }
        out_idx[n] = (float)bi;
    }
}

// -------------------- gather + STE output + loss partials + segment sums -
__global__ __launch_bounds__(256) void k_quant(
    const float* __restrict__ x, const float* __restrict__ w,
    const float* __restrict__ idxf, float* __restrict__ out0,
    float* __restrict__ sums, int* __restrict__ counts,
    double* __restrict__ lpart) {
    const int gid = blockIdx.x * 256 + threadIdx.x;
    const int n = gid >> 6, d = gid & 63;
    const int idx = (int)idxf[n];
    const float in = x[gid];
    const float q  = w[idx * D_DIM + d];
    out0[gid] = in + (q - in);               // straight-through
    const float diff = in - q;
    atomicAdd(&sums[idx * D_DIM + d], in);
    if (d == 0) atomicAdd(&counts[idx], 1);

    __shared__ double red[256];
    red[threadIdx.x] = (double)diff * (double)diff;
    __syncthreads();
    for (int s = 128; s > 0; s >>= 1) {
        if (threadIdx.x < s) red[threadIdx.x] += red[threadIdx.x + s];
        __syncthreads();
    }
    if (threadIdx.x == 0) lpart[blockIdx.x] = red[0];
}

// -------------------- loss finalize (deterministic) ----------------------
__global__ void k_loss(const double* __restrict__ lpart, float* __restrict__ out1) {
    __shared__ double red[256];
    double s = 0.0;
    for (int i = threadIdx.x; i < 8192; i += 256) s += lpart[i];
    red[threadIdx.x] = s;
    __syncthreads();
    for (int st = 128; st > 0; st >>= 1) {
        if (threadIdx.x < st) red[threadIdx.x] += red[threadIdx.x + st];
        __syncthreads();
    }
    if (threadIdx.x == 0) out1[0] = (float)(0.25 * red[0] / (double)NELEM);
}

// -------------------- ema_cs + partial sums for n ------------------------
__global__ void k_emacs(const float* __restrict__ old_cs, const int* __restrict__ counts,
                        float* __restrict__ out4, double* __restrict__ cspart) {
    const int k = blockIdx.x * 256 + threadIdx.x;
    const float e = 0.99f * old_cs[k] + 0.01f * (float)counts[k];
    out4[k] = e;
    __shared__ double red[256];
    red[threadIdx.x] = (double)e;
    __syncthreads();
    for (int s = 128; s > 0; s >>= 1) {
        if (threadIdx.x < s) red[threadIdx.x] += red[threadIdx.x + s];
        __syncthreads();
    }
    if (threadIdx.x == 0) cspart[blockIdx.x] = red[0];
}

// -------------------- ema_es + new_weight --------------------------------
__global__ __launch_bounds__(256) void k_final(
    const float* __restrict__ old_es, const float* __restrict__ sums,
    const float* __restrict__ out4, const double* __restrict__ cspart,
    float* __restrict__ out3, float* __restrict__ out5) {
    double nd = 0.0;
#pragma unroll
    for (int i = 0; i < 16; ++i) nd += cspart[i];
    const float nf = (float)nd;
    const int gid = blockIdx.x * 256 + threadIdx.x;
    const int k = gid >> 6;
    const float es = 0.99f * old_es[gid] + 0.01f * sums[gid];
    out5[gid] = es;
    const float cs = out4[k];
    const float cssm = (cs + 1e-5f) / (nf + 4096.0f * 1e-5f) * nf;
    out3[gid] = es / cssm;
}

extern "C" void kernel_launch(void* const* d_in, const int* in_sizes, int n_in,
                              void* d_out, int out_size, void* d_ws, size_t ws_size,
                              hipStream_t stream) {
    const float* x      = (const float*)d_in[0];
    const float* w      = (const float*)d_in[1];
    const float* old_cs = (const float*)d_in[2];
    const float* old_es = (const float*)d_in[3];

    float* o    = (float*)d_out;
    float* out0 = o + OUT0_OFF;
    float* out1 = o + OUT1_OFF;
    float* out2 = o + OUT2_OFF;
    float* out3 = o + OUT3_OFF;
    float* out4 = o + OUT4_OFF;
    float* out5 = o + OUT5_OFF;

    char* ws = (char*)d_ws;
    float*  bnorm   = (float*)(ws + WS_BNORM);
    int*    counts  = (int*)(ws + WS_COUNTS);
    float*  sums    = (float*)(ws + WS_SUMS);
    double* lpart   = (double*)(ws + WS_LPART);
    double* cspart  = (double*)(ws + WS_CSPART);

    hipMemsetAsync(counts, 0, K_CODES * sizeof(int), stream);
    hipMemsetAsync(sums, 0, K_CODES * D_DIM * sizeof(float), stream);

    k_bnorm<<<K_CODES / 256, 256, 0, stream>>>(w, bnorm);
    k_score<<<N_VEC / 64, 256, 0, stream>>>(x, w, bnorm, out2);
    k_quant<<<NELEM / 256, 256, 0, stream>>>(x, w, out2, out0, sums, counts, lpart);
    k_loss<<<1, 256, 0, stream>>>(lpart, out1);
    k_emacs<<<K_CODES / 256, 256, 0, stream>>>(old_cs, counts, out4, cspart);
    k_final<<<K_CODES * D_DIM / 256, 256, 0, stream>>>(old_es, sums, out4, cspart,
                                                       out3, out5);
}

// Round 5
// 382.735 us; speedup vs baseline: 3.1071x; 3.1071x over previous
//
#include <hip/hip_runtime.h>

#define N_VEC   32768      // 32*1024
#define K_CODES 4096
#define D_DIM   64
#define NELEM   2097152    // N_VEC * D_DIM

// ---- output layout (floats, concatenated in reference return order) ----
#define OUT0_OFF 0           // quantized_st  (2097152)
#define OUT1_OFF 2097152     // loss          (1)
#define OUT2_OFF 2097153     // indices       (32768)
#define OUT3_OFF 2129921     // new_weight    (262144)
#define OUT4_OFF 2392065     // ema_cs        (4096)
#define OUT5_OFF 2396161     // ema_es        (262144)

// ---- ws layout (byte offsets, 8-aligned) ----
#define WS_BNORM   0            // float[4096]       (16384 B)  np-exact ||w_k||^2
#define WS_COUNTS  16384        // int[4096]         (16384 B)
#define WS_SUMS    32768        // float[4096*64]    (1048576 B)
#define WS_LPART   1081344      // double[8192]      (65536 B)
#define WS_CSPART  1146880      // double[16]        (128 B)

// numpy pairwise_sum base case (n=64): 8 accumulators strided by 8,
// sequential adds, fixed combine tree. sq[] must be PRE-ROUNDED squares.
__device__ __forceinline__ float np_pairwise64(const float* sq) {
    float r0 = sq[0], r1 = sq[1], r2 = sq[2], r3 = sq[3];
    float r4 = sq[4], r5 = sq[5], r6 = sq[6], r7 = sq[7];
#pragma unroll
    for (int b = 8; b < 64; b += 8) {
        r0 = __fadd_rn(r0, sq[b + 0]); r1 = __fadd_rn(r1, sq[b + 1]);
        r2 = __fadd_rn(r2, sq[b + 2]); r3 = __fadd_rn(r3, sq[b + 3]);
        r4 = __fadd_rn(r4, sq[b + 4]); r5 = __fadd_rn(r5, sq[b + 5]);
        r6 = __fadd_rn(r6, sq[b + 6]); r7 = __fadd_rn(r7, sq[b + 7]);
    }
    return __fadd_rn(__fadd_rn(__fadd_rn(r0, r1), __fadd_rn(r2, r3)),
                     __fadd_rn(__fadd_rn(r4, r5), __fadd_rn(r6, r7)));
}

// -------- B_k = np.sum(w_k*w_k) with numpy fp32 semantics ----------------
__global__ void k_bnorm(const float* __restrict__ w, float* __restrict__ bn) {
    int k = blockIdx.x * 256 + threadIdx.x;
    const float* wr = w + k * D_DIM;
    float sq[64];
#pragma unroll
    for (int i = 0; i < 64; ++i) { float v = wr[i]; sq[i] = __fmul_rn(v, v); }
    bn[k] = np_pairwise64(sq);
}

// -------- scorer: bit-replicate np fp32 distances, argmin first-index ----
// Block = 256 threads = 4 waves. Wave wid owns k-slice [wid*1024,(wid+1)*1024);
// each of its 64 lanes owns row n = blockIdx*64 + lane. k0 is made provably
// wave-uniform (readfirstlane) so w/bn loads can go SMEM (scalar pipe).
// x is held in 16 named float4 VGPRs and PINNED with an opaque asm so the
// compiler cannot re-materialize the loads inside the loop (R4: 8.6 GB of
// x re-fetch = the whole kernel time).
// d_nk = fl( fl(A_n + B_k) - 2*C_nk ), C_nk = ascending-d fp32 FMA chain.
#define CH4(acc, xc, wc)                                \
    acc = __fmaf_rn((xc).x, (wc).x, acc);               \
    acc = __fmaf_rn((xc).y, (wc).y, acc);               \
    acc = __fmaf_rn((xc).z, (wc).z, acc);               \
    acc = __fmaf_rn((xc).w, (wc).w, acc);

#define STEP(c, xc)                                     \
    { float4 u0 = w0[c], u1 = w1[c], u2 = w2[c], u3 = w3[c]; \
      CH4(a0, xc, u0); CH4(a1, xc, u1);                 \
      CH4(a2, xc, u2); CH4(a3, xc, u3); }

#define SQ4(j, xc)                                      \
    sq[4*(j)+0] = __fmul_rn((xc).x, (xc).x);            \
    sq[4*(j)+1] = __fmul_rn((xc).y, (xc).y);            \
    sq[4*(j)+2] = __fmul_rn((xc).z, (xc).z);            \
    sq[4*(j)+3] = __fmul_rn((xc).w, (xc).w);

#define PIN(v) asm volatile("" : "+v"((v).x), "+v"((v).y), "+v"((v).z), "+v"((v).w))

__global__ __launch_bounds__(256, 2) void k_score(
    const float* __restrict__ x, const float* __restrict__ w,
    const float* __restrict__ bn, float* __restrict__ out_idx) {
    const int lane = threadIdx.x & 63;
    const int n    = blockIdx.x * 64 + lane;
    // wave-uniform slice id, provably uniform for the compiler -> SMEM loads
    const int wid_u = __builtin_amdgcn_readfirstlane(threadIdx.x >> 6);
    const int k0    = wid_u * 1024;

    const float4* xr = (const float4*)(x + (size_t)n * D_DIM);
    float4 x0 = xr[0],  x1 = xr[1],  x2 = xr[2],  x3 = xr[3];
    float4 x4 = xr[4],  x5 = xr[5],  x6 = xr[6],  x7 = xr[7];
    float4 x8 = xr[8],  x9 = xr[9],  x10 = xr[10], x11 = xr[11];
    float4 x12 = xr[12], x13 = xr[13], x14 = xr[14], x15 = xr[15];
    PIN(x0);  PIN(x1);  PIN(x2);  PIN(x3);
    PIN(x4);  PIN(x5);  PIN(x6);  PIN(x7);
    PIN(x8);  PIN(x9);  PIN(x10); PIN(x11);
    PIN(x12); PIN(x13); PIN(x14); PIN(x15);

    // A_n: numpy-exact sum of pre-rounded squares
    float A;
    {
        float sq[64];
        SQ4(0, x0);  SQ4(1, x1);  SQ4(2, x2);  SQ4(3, x3);
        SQ4(4, x4);  SQ4(5, x5);  SQ4(6, x6);  SQ4(7, x7);
        SQ4(8, x8);  SQ4(9, x9);  SQ4(10, x10); SQ4(11, x11);
        SQ4(12, x12); SQ4(13, x13); SQ4(14, x14); SQ4(15, x15);
        A = np_pairwise64(sq);
    }

    float bestd = 3.4e38f;
    int   besti = k0;
    for (int kb = k0; kb < k0 + 1024; kb += 4) {
        const float4* w0 = (const float4*)(w + (size_t)(kb + 0) * D_DIM);
        const float4* w1 = (const float4*)(w + (size_t)(kb + 1) * D_DIM);
        const float4* w2 = (const float4*)(w + (size_t)(kb + 2) * D_DIM);
        const float4* w3 = (const float4*)(w + (size_t)(kb + 3) * D_DIM);
        float a0 = 0.f, a1 = 0.f, a2 = 0.f, a3 = 0.f;
        STEP(0, x0);  STEP(1, x1);  STEP(2, x2);  STEP(3, x3);
        STEP(4, x4);  STEP(5, x5);  STEP(6, x6);  STEP(7, x7);
        STEP(8, x8);  STEP(9, x9);  STEP(10, x10); STEP(11, x11);
        STEP(12, x12); STEP(13, x13); STEP(14, x14); STEP(15, x15);
        float d0 = __fsub_rn(__fadd_rn(A, bn[kb + 0]), __fmul_rn(2.0f, a0));
        float d1 = __fsub_rn(__fadd_rn(A, bn[kb + 1]), __fmul_rn(2.0f, a1));
        float d2 = __fsub_rn(__fadd_rn(A, bn[kb + 2]), __fmul_rn(2.0f, a2));
        float d3 = __fsub_rn(__fadd_rn(A, bn[kb + 3]), __fmul_rn(2.0f, a3));
        if (d0 < bestd) { bestd = d0; besti = kb + 0; }   // ascending k:
        if (d1 < bestd) { bestd = d1; besti = kb + 1; }   // strict < keeps
        if (d2 < bestd) { bestd = d2; besti = kb + 2; }   // first min, like
        if (d3 < bestd) { bestd = d3; besti = kb + 3; }   // np.argmin
    }

    // merge the 4 k-slices (ascending slice order preserves first-min)
    __shared__ float sbd[4][64];
    __shared__ int   sbi[4][64];
    sbd[wid_u][lane] = bestd;
    sbi[wid_u][lane] = besti;
    __syncthreads();
    if (threadIdx.x < 64) {
        float bd = sbd[0][lane];
        int   bi = sbi[0][lane];
#pragma unroll
        for (int s = 1; s < 4; ++s) {
            float od = sbd[s][lane];
            int   oi = sbi[s][lane];
            if (od < bd) { bd = od; bi = oi; }   // strict <: lower slice wins ties
        }
        out_idx[n] = (float)bi;
    }
}

// -------------------- gather + STE output + loss partials + segment sums -
__global__ __launch_bounds__(256) void k_quant(
    const float* __restrict__ x, const float* __restrict__ w,
    const float* __restrict__ idxf, float* __restrict__ out0,
    float* __restrict__ sums, int* __restrict__ counts,
    double* __restrict__ lpart) {
    const int gid = blockIdx.x * 256 + threadIdx.x;
    const int n = gid >> 6, d = gid & 63;
    const int idx = (int)idxf[n];
    const float in = x[gid];
    const float q  = w[idx * D_DIM + d];
    out0[gid] = in + (q - in);               // straight-through
    const float diff = in - q;
    atomicAdd(&sums[idx * D_DIM + d], in);
    if (d == 0) atomicAdd(&counts[idx], 1);

    __shared__ double red[256];
    red[threadIdx.x] = (double)diff * (double)diff;
    __syncthreads();
    for (int s = 128; s > 0; s >>= 1) {
        if (threadIdx.x < s) red[threadIdx.x] += red[threadIdx.x + s];
        __syncthreads();
    }
    if (threadIdx.x == 0) lpart[blockIdx.x] = red[0];
}

// -------------------- loss finalize (deterministic) ----------------------
__global__ void k_loss(const double* __restrict__ lpart, float* __restrict__ out1) {
    __shared__ double red[256];
    double s = 0.0;
    for (int i = threadIdx.x; i < 8192; i += 256) s += lpart[i];
    red[threadIdx.x] = s;
    __syncthreads();
    for (int st = 128; st > 0; st >>= 1) {
        if (threadIdx.x < st) red[threadIdx.x] += red[threadIdx.x + st];
        __syncthreads();
    }
    if (threadIdx.x == 0) out1[0] = (float)(0.25 * red[0] / (double)NELEM);
}

// -------------------- ema_cs + partial sums for n ------------------------
__global__ void k_emacs(const float* __restrict__ old_cs, const int* __restrict__ counts,
                        float* __restrict__ out4, double* __restrict__ cspart) {
    const int k = blockIdx.x * 256 + threadIdx.x;
    const float e = 0.99f * old_cs[k] + 0.01f * (float)counts[k];
    out4[k] = e;
    __shared__ double red[256];
    red[threadIdx.x] = (double)e;
    __syncthreads();
    for (int s = 128; s > 0; s >>= 1) {
        if (threadIdx.x < s) red[threadIdx.x] += red[threadIdx.x + s];
        __syncthreads();
    }
    if (threadIdx.x == 0) cspart[blockIdx.x] = red[0];
}

// -------------------- ema_es + new_weight --------------------------------
__global__ __launch_bounds__(256) void k_final(
    const float* __restrict__ old_es, const float* __restrict__ sums,
    const float* __restrict__ out4, const double* __restrict__ cspart,
    float* __restrict__ out3, float* __restrict__ out5) {
    double nd = 0.0;
#pragma unroll
    for (int i = 0; i < 16; ++i) nd += cspart[i];
    const float nf = (float)nd;
    const int gid = blockIdx.x * 256 + threadIdx.x;
    const int k = gid >> 6;
    const float es = 0.99f * old_es[gid] + 0.01f * sums[gid];
    out5[gid] = es;
    const float cs = out4[k];
    const float cssm = (cs + 1e-5f) / (nf + 4096.0f * 1e-5f) * nf;
    out3[gid] = es / cssm;
}

extern "C" void kernel_launch(void* const* d_in, const int* in_sizes, int n_in,
                              void* d_out, int out_size, void* d_ws, size_t ws_size,
                              hipStream_t stream) {
    const float* x      = (const float*)d_in[0];
    const float* w      = (const float*)d_in[1];
    const float* old_cs = (const float*)d_in[2];
    const float* old_es = (const float*)d_in[3];

    float* o    = (float*)d_out;
    float* out0 = o + OUT0_OFF;
    float* out1 = o + OUT1_OFF;
    float* out2 = o + OUT2_OFF;
    float* out3 = o + OUT3_OFF;
    float* out4 = o + OUT4_OFF;
    float* out5 = o + OUT5_OFF;

    char* ws = (char*)d_ws;
    float*  bnorm   = (float*)(ws + WS_BNORM);
    int*    counts  = (int*)(ws + WS_COUNTS);
    float*  sums    = (float*)(ws + WS_SUMS);
    double* lpart   = (double*)(ws + WS_LPART);
    double* cspart  = (double*)(ws + WS_CSPART);

    hipMemsetAsync(counts, 0, K_CODES * sizeof(int), stream);
    hipMemsetAsync(sums, 0, K_CODES * D_DIM * sizeof(float), stream);

    k_bnorm<<<K_CODES / 256, 256, 0, stream>>>(w, bnorm);
    k_score<<<N_VEC / 64, 256, 0, stream>>>(x, w, bnorm, out2);
    k_quant<<<NELEM / 256, 256, 0, stream>>>(x, w, out2, out0, sums, counts, lpart);
    k_loss<<<1, 256, 0, stream>>>(lpart, out1);
    k_emacs<<<K_CODES / 256, 256, 0, stream>>>(old_cs, counts, out4, cspart);
    k_final<<<K_CODES * D_DIM / 256, 256, 0, stream>>>(old_es, sums, out4, cspart,
                                                       out3, out5);
}

// Round 6
// 313.550 us; speedup vs baseline: 3.7927x; 1.2207x over previous
//
#include <hip/hip_runtime.h>

#define N_VEC   32768      // 32*1024
#define K_CODES 4096
#define D_DIM   64
#define NELEM   2097152    // N_VEC * D_DIM

// ---- output layout (floats, concatenated in reference return order) ----
#define OUT0_OFF 0           // quantized_st  (2097152)
#define OUT1_OFF 2097152     // loss          (1)
#define OUT2_OFF 2097153     // indices       (32768)
#define OUT3_OFF 2129921     // new_weight    (262144)
#define OUT4_OFF 2392065     // ema_cs        (4096)
#define OUT5_OFF 2396161     // ema_es        (262144)

// ---- ws layout (byte offsets, 8-aligned) ----
#define WS_BNORM   0            // float[4096]       (16384 B)  np-exact ||w_k||^2
#define WS_COUNTS  16384        // int[4096]         (16384 B)
#define WS_SUMS    32768        // float[4096*64]    (1048576 B)
#define WS_LPART   1081344      // double[8192]      (65536 B)
#define WS_CSPART  1146880      // double[16]        (128 B)
#define WS_PD      1147008      // float[4*32768]    (524288 B) per-chunk best dist
#define WS_PI      1671296      // int[4*32768]      (524288 B) per-chunk best idx

// numpy pairwise_sum base case (n=64): 8 accumulators strided by 8,
// sequential adds, fixed combine tree. sq[] must be PRE-ROUNDED squares.
__device__ __forceinline__ float np_pairwise64(const float* sq) {
    float r0 = sq[0], r1 = sq[1], r2 = sq[2], r3 = sq[3];
    float r4 = sq[4], r5 = sq[5], r6 = sq[6], r7 = sq[7];
#pragma unroll
    for (int b = 8; b < 64; b += 8) {
        r0 = __fadd_rn(r0, sq[b + 0]); r1 = __fadd_rn(r1, sq[b + 1]);
        r2 = __fadd_rn(r2, sq[b + 2]); r3 = __fadd_rn(r3, sq[b + 3]);
        r4 = __fadd_rn(r4, sq[b + 4]); r5 = __fadd_rn(r5, sq[b + 5]);
        r6 = __fadd_rn(r6, sq[b + 6]); r7 = __fadd_rn(r7, sq[b + 7]);
    }
    return __fadd_rn(__fadd_rn(__fadd_rn(r0, r1), __fadd_rn(r2, r3)),
                     __fadd_rn(__fadd_rn(r4, r5), __fadd_rn(r6, r7)));
}

// -------- B_k = np.sum(w_k*w_k) with numpy fp32 semantics ----------------
__global__ void k_bnorm(const float* __restrict__ w, float* __restrict__ bn) {
    int k = blockIdx.x * 256 + threadIdx.x;
    const float* wr = w + k * D_DIM;
    float sq[64];
#pragma unroll
    for (int i = 0; i < 64; ++i) { float v = wr[i]; sq[i] = __fmul_rn(v, v); }
    bn[k] = np_pairwise64(sq);
}

// -------- scorer: bit-replicate np fp32 distances, argmin first-index ----
// Grid = 2048 blocks: rg = blockIdx&511 (row group of 64), kc = blockIdx>>9
// (k-chunk of 1024). Block = 4 waves; wave wid covers 256 k. 8192 waves =
// 8 waves/SIMD (R5 was 2/SIMD and latency-bound on L2 w-loads, VALUBusy 57%).
// Consecutive blocks share a 256KB w-chunk -> L2 locality.
// d_nk = fl( fl(A_n + B_k) - 2*C_nk ), C_nk = ascending-d fp32 FMA chain.
#define CH4(acc, xc, wc)                                \
    acc = __fmaf_rn((xc).x, (wc).x, acc);               \
    acc = __fmaf_rn((xc).y, (wc).y, acc);               \
    acc = __fmaf_rn((xc).z, (wc).z, acc);               \
    acc = __fmaf_rn((xc).w, (wc).w, acc);

#define STEP(c, xc)                                     \
    { float4 u0 = w0[c], u1 = w1[c], u2 = w2[c], u3 = w3[c]; \
      CH4(a0, xc, u0); CH4(a1, xc, u1);                 \
      CH4(a2, xc, u2); CH4(a3, xc, u3); }

#define SQ4(j, xc)                                      \
    sq[4*(j)+0] = __fmul_rn((xc).x, (xc).x);            \
    sq[4*(j)+1] = __fmul_rn((xc).y, (xc).y);            \
    sq[4*(j)+2] = __fmul_rn((xc).z, (xc).z);            \
    sq[4*(j)+3] = __fmul_rn((xc).w, (xc).w);

#define PIN(v) asm volatile("" : "+v"((v).x), "+v"((v).y), "+v"((v).z), "+v"((v).w))

__global__ __launch_bounds__(256, 2) void k_score(
    const float* __restrict__ x, const float* __restrict__ w,
    const float* __restrict__ bn, float* __restrict__ pd,
    int* __restrict__ pi) {
    const int lane = threadIdx.x & 63;
    const int rg   = blockIdx.x & 511;
    const int kc   = blockIdx.x >> 9;           // 0..3
    const int n    = rg * 64 + lane;
    // wave-uniform slice id, provably uniform for the compiler -> scalar loads
    const int wid_u = __builtin_amdgcn_readfirstlane(threadIdx.x >> 6);
    const int k0    = kc * 1024 + wid_u * 256;

    const float4* xr = (const float4*)(x + (size_t)n * D_DIM);
    float4 x0 = xr[0],  x1 = xr[1],  x2 = xr[2],  x3 = xr[3];
    float4 x4 = xr[4],  x5 = xr[5],  x6 = xr[6],  x7 = xr[7];
    float4 x8 = xr[8],  x9 = xr[9],  x10 = xr[10], x11 = xr[11];
    float4 x12 = xr[12], x13 = xr[13], x14 = xr[14], x15 = xr[15];
    PIN(x0);  PIN(x1);  PIN(x2);  PIN(x3);
    PIN(x4);  PIN(x5);  PIN(x6);  PIN(x7);
    PIN(x8);  PIN(x9);  PIN(x10); PIN(x11);
    PIN(x12); PIN(x13); PIN(x14); PIN(x15);

    // A_n: numpy-exact sum of pre-rounded squares (identical bits per block)
    float A;
    {
        float sq[64];
        SQ4(0, x0);  SQ4(1, x1);  SQ4(2, x2);  SQ4(3, x3);
        SQ4(4, x4);  SQ4(5, x5);  SQ4(6, x6);  SQ4(7, x7);
        SQ4(8, x8);  SQ4(9, x9);  SQ4(10, x10); SQ4(11, x11);
        SQ4(12, x12); SQ4(13, x13); SQ4(14, x14); SQ4(15, x15);
        A = np_pairwise64(sq);
    }

    float bestd = 3.4e38f;
    int   besti = k0;
    for (int kb = k0; kb < k0 + 256; kb += 4) {
        const float4* w0 = (const float4*)(w + (size_t)(kb + 0) * D_DIM);
        const float4* w1 = (const float4*)(w + (size_t)(kb + 1) * D_DIM);
        const float4* w2 = (const float4*)(w + (size_t)(kb + 2) * D_DIM);
        const float4* w3 = (const float4*)(w + (size_t)(kb + 3) * D_DIM);
        float a0 = 0.f, a1 = 0.f, a2 = 0.f, a3 = 0.f;
        STEP(0, x0);  STEP(1, x1);  STEP(2, x2);  STEP(3, x3);
        STEP(4, x4);  STEP(5, x5);  STEP(6, x6);  STEP(7, x7);
        STEP(8, x8);  STEP(9, x9);  STEP(10, x10); STEP(11, x11);
        STEP(12, x12); STEP(13, x13); STEP(14, x14); STEP(15, x15);
        float d0 = __fsub_rn(__fadd_rn(A, bn[kb + 0]), __fmul_rn(2.0f, a0));
        float d1 = __fsub_rn(__fadd_rn(A, bn[kb + 1]), __fmul_rn(2.0f, a1));
        float d2 = __fsub_rn(__fadd_rn(A, bn[kb + 2]), __fmul_rn(2.0f, a2));
        float d3 = __fsub_rn(__fadd_rn(A, bn[kb + 3]), __fmul_rn(2.0f, a3));
        if (d0 < bestd) { bestd = d0; besti = kb + 0; }   // ascending k:
        if (d1 < bestd) { bestd = d1; besti = kb + 1; }   // strict < keeps
        if (d2 < bestd) { bestd = d2; besti = kb + 2; }   // first min, like
        if (d3 < bestd) { bestd = d3; besti = kb + 3; }   // np.argmin
    }

    // merge the 4 waves (ascending wid = ascending k within this chunk)
    __shared__ float sbd[4][64];
    __shared__ int   sbi[4][64];
    sbd[wid_u][lane] = bestd;
    sbi[wid_u][lane] = besti;
    __syncthreads();
    if (threadIdx.x < 64) {
        float bd = sbd[0][lane];
        int   bi = sbi[0][lane];
#pragma unroll
        for (int s = 1; s < 4; ++s) {
            float od = sbd[s][lane];
            int   oi = sbi[s][lane];
            if (od < bd) { bd = od; bi = oi; }   // strict <: lower slice wins ties
        }
        pd[kc * N_VEC + n] = bd;
        pi[kc * N_VEC + n] = bi;
    }
}

// -------- merge the 4 k-chunks (ascending chunk preserves first-min) -----
__global__ void k_amerge(const float* __restrict__ pd, const int* __restrict__ pi,
                         float* __restrict__ out_idx) {
    const int n = blockIdx.x * 256 + threadIdx.x;
    float bd = pd[n];
    int   bi = pi[n];
#pragma unroll
    for (int c = 1; c < 4; ++c) {
        float od = pd[c * N_VEC + n];
        int   oi = pi[c * N_VEC + n];
        if (od < bd) { bd = od; bi = oi; }       // strict <: lower chunk wins ties
    }
    out_idx[n] = (float)bi;
}

// -------------------- gather + STE output + loss partials + segment sums -
__global__ __launch_bounds__(256) void k_quant(
    const float* __restrict__ x, const float* __restrict__ w,
    const float* __restrict__ idxf, float* __restrict__ out0,
    float* __restrict__ sums, int* __restrict__ counts,
    double* __restrict__ lpart) {
    const int gid = blockIdx.x * 256 + threadIdx.x;
    const int n = gid >> 6, d = gid & 63;
    const int idx = (int)idxf[n];
    const float in = x[gid];
    const float q  = w[idx * D_DIM + d];
    out0[gid] = in + (q - in);               // straight-through
    const float diff = in - q;
    atomicAdd(&sums[idx * D_DIM + d], in);
    if (d == 0) atomicAdd(&counts[idx], 1);

    __shared__ double red[256];
    red[threadIdx.x] = (double)diff * (double)diff;
    __syncthreads();
    for (int s = 128; s > 0; s >>= 1) {
        if (threadIdx.x < s) red[threadIdx.x] += red[threadIdx.x + s];
        __syncthreads();
    }
    if (threadIdx.x == 0) lpart[blockIdx.x] = red[0];
}

// -------------------- loss finalize (deterministic) ----------------------
__global__ void k_loss(const double* __restrict__ lpart, float* __restrict__ out1) {
    __shared__ double red[256];
    double s = 0.0;
    for (int i = threadIdx.x; i < 8192; i += 256) s += lpart[i];
    red[threadIdx.x] = s;
    __syncthreads();
    for (int st = 128; st > 0; st >>= 1) {
        if (threadIdx.x < st) red[threadIdx.x] += red[threadIdx.x + st];
        __syncthreads();
    }
    if (threadIdx.x == 0) out1[0] = (float)(0.25 * red[0] / (double)NELEM);
}

// -------------------- ema_cs + partial sums for n ------------------------
__global__ void k_emacs(const float* __restrict__ old_cs, const int* __restrict__ counts,
                        float* __restrict__ out4, double* __restrict__ cspart) {
    const int k = blockIdx.x * 256 + threadIdx.x;
    const float e = 0.99f * old_cs[k] + 0.01f * (float)counts[k];
    out4[k] = e;
    __shared__ double red[256];
    red[threadIdx.x] = (double)e;
    __syncthreads();
    for (int s = 128; s > 0; s >>= 1) {
        if (threadIdx.x < s) red[threadIdx.x] += red[threadIdx.x + s];
        __syncthreads();
    }
    if (threadIdx.x == 0) cspart[blockIdx.x] = red[0];
}

// -------------------- ema_es + new_weight --------------------------------
__global__ __launch_bounds__(256) void k_final(
    const float* __restrict__ old_es, const float* __restrict__ sums,
    const float* __restrict__ out4, const double* __restrict__ cspart,
    float* __restrict__ out3, float* __restrict__ out5) {
    double nd = 0.0;
#pragma unroll
    for (int i = 0; i < 16; ++i) nd += cspart[i];
    const float nf = (float)nd;
    const int gid = blockIdx.x * 256 + threadIdx.x;
    const int k = gid >> 6;
    const float es = 0.99f * old_es[gid] + 0.01f * sums[gid];
    out5[gid] = es;
    const float cs = out4[k];
    const float cssm = (cs + 1e-5f) / (nf + 4096.0f * 1e-5f) * nf;
    out3[gid] = es / cssm;
}

extern "C" void kernel_launch(void* const* d_in, const int* in_sizes, int n_in,
                              void* d_out, int out_size, void* d_ws, size_t ws_size,
                              hipStream_t stream) {
    const float* x      = (const float*)d_in[0];
    const float* w      = (const float*)d_in[1];
    const float* old_cs = (const float*)d_in[2];
    const float* old_es = (const float*)d_in[3];

    float* o    = (float*)d_out;
    float* out0 = o + OUT0_OFF;
    float* out1 = o + OUT1_OFF;
    float* out2 = o + OUT2_OFF;
    float* out3 = o + OUT3_OFF;
    float* out4 = o + OUT4_OFF;
    float* out5 = o + OUT5_OFF;

    char* ws = (char*)d_ws;
    float*  bnorm   = (float*)(ws + WS_BNORM);
    int*    counts  = (int*)(ws + WS_COUNTS);
    float*  sums    = (float*)(ws + WS_SUMS);
    double* lpart   = (double*)(ws + WS_LPART);
    double* cspart  = (double*)(ws + WS_CSPART);
    float*  pd      = (float*)(ws + WS_PD);
    int*    pi      = (int*)(ws + WS_PI);

    hipMemsetAsync(counts, 0, K_CODES * sizeof(int), stream);
    hipMemsetAsync(sums, 0, K_CODES * D_DIM * sizeof(float), stream);

    k_bnorm<<<K_CODES / 256, 256, 0, stream>>>(w, bnorm);
    k_score<<<2048, 256, 0, stream>>>(x, w, bnorm, pd, pi);
    k_amerge<<<N_VEC / 256, 256, 0, stream>>>(pd, pi, out2);
    k_quant<<<NELEM / 256, 256, 0, stream>>>(x, w, out2, out0, sums, counts, lpart);
    k_loss<<<1, 256, 0, stream>>>(lpart, out1);
    k_emacs<<<K_CODES / 256, 256, 0, stream>>>(old_cs, counts, out4, cspart);
    k_final<<<K_CODES * D_DIM / 256, 256, 0, stream>>>(old_es, sums, out4, cspart,
                                                       out3, out5);
}

// Round 9
// 167.947 us; speedup vs baseline: 7.0808x; 1.8670x over previous
//
#include <hip/hip_runtime.h>

#define N_VEC   32768      // 32*1024
#define K_CODES 4096
#define D_DIM   64
#define NELEM   2097152    // N_VEC * D_DIM
#define TH_APPROX 7.5e-4f

// ---- output layout (floats, concatenated in reference return order) ----
#define OUT0_OFF 0           // quantized_st  (2097152)
#define OUT1_OFF 2097152     // loss          (1)
#define OUT2_OFF 2097153     // indices       (32768)
#define OUT3_OFF 2129921     // new_weight    (262144)
#define OUT4_OFF 2392065     // ema_cs        (4096)
#define OUT5_OFF 2396161     // ema_es        (262144)

// ---- ws layout (byte offsets). Overlays are stream-ordered safe:
//  CANDS (approx/rescore) overlays SUMS (k_quant, memset AFTER rescore)
//  WBF (approx) overlays LPART/CSPART (k_quant/k_emacs, written later)
#define WS_BNORM   0            // float[4096]
#define WS_COUNTS  16384        // int[4096]
#define WS_CANDC   32768        // int[32768]
#define WS_CANDS   163840       // ushort[32768*16]  (1048576 B)
#define WS_SUMS    163840       // float[262144]     (1048576 B) overlay
#define WS_WBF     1212416      // short[262144]     (524288 B)
#define WS_LPART   1212416      // double[8192]      overlay
#define WS_CSPART  1277952      // double[16]        overlay
// total footprint 1736704 B

typedef short  s16x8 __attribute__((ext_vector_type(8)));
typedef float  f32x4 __attribute__((ext_vector_type(4)));

__device__ __forceinline__ unsigned short bf16rne(float f) {
    unsigned u = __float_as_uint(f);
    unsigned r = u + 0x7fffu + ((u >> 16) & 1u);
    return (unsigned short)(r >> 16);
}

// numpy pairwise_sum base case (n=64): 8 accumulators strided by 8,
// sequential adds, fixed combine tree. sq[] must be PRE-ROUNDED squares.
__device__ __forceinline__ float np_pairwise64(const float* sq) {
    float r0 = sq[0], r1 = sq[1], r2 = sq[2], r3 = sq[3];
    float r4 = sq[4], r5 = sq[5], r6 = sq[6], r7 = sq[7];
#pragma unroll
    for (int b = 8; b < 64; b += 8) {
        r0 = __fadd_rn(r0, sq[b + 0]); r1 = __fadd_rn(r1, sq[b + 1]);
        r2 = __fadd_rn(r2, sq[b + 2]); r3 = __fadd_rn(r3, sq[b + 3]);
        r4 = __fadd_rn(r4, sq[b + 4]); r5 = __fadd_rn(r5, sq[b + 5]);
        r6 = __fadd_rn(r6, sq[b + 6]); r7 = __fadd_rn(r7, sq[b + 7]);
    }
    return __fadd_rn(__fadd_rn(__fadd_rn(r0, r1), __fadd_rn(r2, r3)),
                     __fadd_rn(__fadd_rn(r4, r5), __fadd_rn(r6, r7)));
}

// -------- B_k = np.sum(w_k*w_k) with numpy fp32 semantics ----------------
__global__ void k_bnorm(const float* __restrict__ w, float* __restrict__ bn) {
    int k = blockIdx.x * 256 + threadIdx.x;
    const float* wr = w + k * D_DIM;
    float sq[64];
#pragma unroll
    for (int i = 0; i < 64; ++i) { float v = wr[i]; sq[i] = __fmul_rn(v, v); }
    bn[k] = np_pairwise64(sq);
}

// -------- w -> bf16 ------------------------------------------------------
__global__ void k_wcvtbf(const float* __restrict__ w, short* __restrict__ wbf) {
    int gid = blockIdx.x * 256 + threadIdx.x;
    wbf[gid] = (short)bf16rne(w[gid]);
}

// -------- MFMA approx scorer + candidate collection ----------------------
// Block = 64 rows x all 4096 codewords; 4 waves, wave wid owns cols
// [wid*1024, +1024). x staged once in LDS as bf16; A-frags hoisted to regs
// (identical for every col-tile). Sweep1: per-row min of m = bn_k - 2*C~.
// Sweep2: recompute, collect k with m <= rowmin + TH (cap 16, overflow ->
// full exact scan in k_rescore).
// mfma_f32_16x16x32_bf16 layouts: A row=l&15, k=(l>>4)*8+e; B col=l&15,
// same k; C col=l&15, row=(l>>4)*4+reg (m89-verified).
#define XLDS_LD 72

__global__ __launch_bounds__(256, 2) void k_approx(
    const float* __restrict__ x, const short* __restrict__ wbf,
    const float* __restrict__ bn, int* __restrict__ candc,
    unsigned short* __restrict__ cands) {
    __shared__ short xlds[64 * XLDS_LD];
    __shared__ float wmin[4][64];
    __shared__ float gmin[64];
    __shared__ int   ccnt[64];

    const int tid  = threadIdx.x;
    const int lane = tid & 63;
    const int wid  = __builtin_amdgcn_readfirstlane(tid >> 6);
    const int rbase = blockIdx.x * 64;
    const int arow = lane & 15;        // A row / B col / C col selector
    const int agrp = lane >> 4;        // k-group / C row group

    // stage x rows -> bf16 LDS (row-major, padded)
    for (int i = tid; i < 64 * 16; i += 256) {
        int r = i >> 4, c4 = i & 15;
        float4 v = ((const float4*)(x + (size_t)(rbase + r) * D_DIM))[c4];
        ushort4 b;
        b.x = bf16rne(v.x); b.y = bf16rne(v.y);
        b.z = bf16rne(v.z); b.w = bf16rne(v.w);
        *(ushort4*)&xlds[r * XLDS_LD + c4 * 4] = b;
    }
    if (tid < 64) ccnt[tid] = 0;
    __syncthreads();

    // hoist A-frags: identical for every col-tile
    s16x8 af0[4], af1[4];
#pragma unroll
    for (int rt = 0; rt < 4; ++rt) {
        af0[rt] = *(const s16x8*)&xlds[(rt * 16 + arow) * XLDS_LD + 0 * 32 + agrp * 8];
        af1[rt] = *(const s16x8*)&xlds[(rt * 16 + arow) * XLDS_LD + 1 * 32 + agrp * 8];
    }

    const int col0base = wid * 1024;

    // ---- sweep 1: running min of m = bn - 2*C~ (per-lane, per C slot) ----
    float rm[16];
#pragma unroll
    for (int i = 0; i < 16; ++i) rm[i] = 3.4e38f;

    for (int tc = 0; tc < 64; ++tc) {
        const int mycol = col0base + tc * 16 + arow;
        s16x8 b0 = *(const s16x8*)&wbf[(size_t)mycol * D_DIM + 0 * 32 + agrp * 8];
        s16x8 b1 = *(const s16x8*)&wbf[(size_t)mycol * D_DIM + 1 * 32 + agrp * 8];
        float bnv = bn[mycol];
#pragma unroll
        for (int rt = 0; rt < 4; ++rt) {
            f32x4 c = {0.f, 0.f, 0.f, 0.f};
            c = __builtin_amdgcn_mfma_f32_16x16x32_bf16(af0[rt], b0, c, 0, 0, 0);
            c = __builtin_amdgcn_mfma_f32_16x16x32_bf16(af1[rt], b1, c, 0, 0, 0);
#pragma unroll
            for (int j = 0; j < 4; ++j) {
                float m = fmaf(-2.0f, c[j], bnv);
                rm[rt * 4 + j] = fminf(rm[rt * 4 + j], m);
            }
        }
    }

    // cross-col (lane&15) min reduce, then block reduce across waves
#pragma unroll
    for (int i = 0; i < 16; ++i) {
        float v = rm[i];
        v = fminf(v, __shfl_xor(v, 1));
        v = fminf(v, __shfl_xor(v, 2));
        v = fminf(v, __shfl_xor(v, 4));
        v = fminf(v, __shfl_xor(v, 8));
        rm[i] = v;
    }
    if (arow == 0) {
#pragma unroll
        for (int i = 0; i < 16; ++i)
            wmin[wid][(i >> 2) * 16 + agrp * 4 + (i & 3)] = rm[i];
    }
    __syncthreads();
    if (tid < 64) {
        float g = fminf(fminf(wmin[0][tid], wmin[1][tid]),
                        fminf(wmin[2][tid], wmin[3][tid]));
        gmin[tid] = g + TH_APPROX;
    }
    __syncthreads();

    // per-lane threshold cache for its 16 C slots
    float gv[16];
#pragma unroll
    for (int i = 0; i < 16; ++i)
        gv[i] = gmin[(i >> 2) * 16 + agrp * 4 + (i & 3)];

    // ---- sweep 2: recompute, collect candidates --------------------------
    for (int tc = 0; tc < 64; ++tc) {
        const int mycol = col0base + tc * 16 + arow;
        s16x8 b0 = *(const s16x8*)&wbf[(size_t)mycol * D_DIM + 0 * 32 + agrp * 8];
        s16x8 b1 = *(const s16x8*)&wbf[(size_t)mycol * D_DIM + 1 * 32 + agrp * 8];
        float bnv = bn[mycol];
#pragma unroll
        for (int rt = 0; rt < 4; ++rt) {
            f32x4 c = {0.f, 0.f, 0.f, 0.f};
            c = __builtin_amdgcn_mfma_f32_16x16x32_bf16(af0[rt], b0, c, 0, 0, 0);
            c = __builtin_amdgcn_mfma_f32_16x16x32_bf16(af1[rt], b1, c, 0, 0, 0);
#pragma unroll
            for (int j = 0; j < 4; ++j) {
                float m = fmaf(-2.0f, c[j], bnv);
                if (m <= gv[rt * 4 + j]) {
                    int row = rt * 16 + agrp * 4 + j;
                    int p = atomicAdd(&ccnt[row], 1);
                    if (p < 16)
                        cands[(size_t)(rbase + row) * 16 + p] = (unsigned short)mycol;
                }
            }
        }
    }
    __syncthreads();
    if (tid < 64) candc[rbase + tid] = ccnt[tid];
}

// -------- exact np rescore of the shortlist ------------------------------
__global__ __launch_bounds__(256) void k_rescore(
    const float* __restrict__ x, const float* __restrict__ w,
    const float* __restrict__ bn, const int* __restrict__ candc,
    const unsigned short* __restrict__ cands, float* __restrict__ out_idx) {
    const int n = blockIdx.x * 256 + threadIdx.x;

    float4 xv[16];
    const float4* xr = (const float4*)(x + (size_t)n * D_DIM);
#pragma unroll
    for (int i = 0; i < 16; ++i) xv[i] = xr[i];

    // A_n: numpy-exact sum of pre-rounded squares
    float A;
    {
        float sq[64];
#pragma unroll
        for (int i = 0; i < 16; ++i) {
            sq[4*i+0] = __fmul_rn(xv[i].x, xv[i].x);
            sq[4*i+1] = __fmul_rn(xv[i].y, xv[i].y);
            sq[4*i+2] = __fmul_rn(xv[i].z, xv[i].z);
            sq[4*i+3] = __fmul_rn(xv[i].w, xv[i].w);
        }
        A = np_pairwise64(sq);
    }

    const int cnt = candc[n];
    float bestd = 3.4e38f;
    int   besti = 0;

    if (cnt <= 16) {
        unsigned short cl[16];
        for (int i = 0; i < cnt; ++i) cl[i] = cands[(size_t)n * 16 + i];
        // sort ascending so strict < reproduces np first-min tie-break
        for (int i = 1; i < cnt; ++i) {
            unsigned short v = cl[i];
            int j = i - 1;
            while (j >= 0 && cl[j] > v) { cl[j + 1] = cl[j]; --j; }
            cl[j + 1] = v;
        }
        for (int i = 0; i < cnt; ++i) {
            const int c = cl[i];
            const float4* wr = (const float4*)(w + (size_t)c * D_DIM);
            float a = 0.f;
#pragma unroll
            for (int ch = 0; ch < 16; ++ch) {
                float4 u = wr[ch];
                a = __fmaf_rn(xv[ch].x, u.x, a);
                a = __fmaf_rn(xv[ch].y, u.y, a);
                a = __fmaf_rn(xv[ch].z, u.z, a);
                a = __fmaf_rn(xv[ch].w, u.w, a);
            }
            float d = __fsub_rn(__fadd_rn(A, bn[c]), __fmul_rn(2.0f, a));
            if (d < bestd) { bestd = d; besti = c; }
        }
    } else {
        // overflow fallback: full exact np scan (P ~ 0)
        for (int c = 0; c < K_CODES; ++c) {
            const float4* wr = (const float4*)(w + (size_t)c * D_DIM);
            float a = 0.f;
#pragma unroll
            for (int ch = 0; ch < 16; ++ch) {
                float4 u = wr[ch];
                a = __fmaf_rn(xv[ch].x, u.x, a);
                a = __fmaf_rn(xv[ch].y, u.y, a);
                a = __fmaf_rn(xv[ch].z, u.z, a);
                a = __fmaf_rn(xv[ch].w, u.w, a);
            }
            float d = __fsub_rn(__fadd_rn(A, bn[c]), __fmul_rn(2.0f, a));
            if (d < bestd) { bestd = d; besti = c; }
        }
    }
    out_idx[n] = (float)besti;
}

// -------------------- gather + STE output + loss partials + segment sums -
__global__ __launch_bounds__(256) void k_quant(
    const float* __restrict__ x, const float* __restrict__ w,
    const float* __restrict__ idxf, float* __restrict__ out0,
    float* __restrict__ sums, int* __restrict__ counts,
    double* __restrict__ lpart) {
    const int gid = blockIdx.x * 256 + threadIdx.x;
    const int n = gid >> 6, d = gid & 63;
    const int idx = (int)idxf[n];
    const float in = x[gid];
    const float q  = w[idx * D_DIM + d];
    out0[gid] = in + (q - in);               // straight-through
    const float diff = in - q;
    atomicAdd(&sums[idx * D_DIM + d], in);
    if (d == 0) atomicAdd(&counts[idx], 1);

    __shared__ double red[256];
    red[threadIdx.x] = (double)diff * (double)diff;
    __syncthreads();
    for (int s = 128; s > 0; s >>= 1) {
        if (threadIdx.x < s) red[threadIdx.x] += red[threadIdx.x + s];
        __syncthreads();
    }
    if (threadIdx.x == 0) lpart[blockIdx.x] = red[0];
}

// -------------------- loss finalize (deterministic) ----------------------
__global__ void k_loss(const double* __restrict__ lpart, float* __restrict__ out1) {
    __shared__ double red[256];
    double s = 0.0;
    for (int i = threadIdx.x; i < 8192; i += 256) s += lpart[i];
    red[threadIdx.x] = s;
    __syncthreads();
    for (int st = 128; st > 0; st >>= 1) {
        if (threadIdx.x < st) red[threadIdx.x] += red[threadIdx.x + st];
        __syncthreads();
    }
    if (threadIdx.x == 0) out1[0] = (float)(0.25 * red[0] / (double)NELEM);
}

// -------------------- ema_cs + partial sums for n ------------------------
__global__ void k_emacs(const float* __restrict__ old_cs, const int* __restrict__ counts,
                        float* __restrict__ out4, double* __restrict__ cspart) {
    const int k = blockIdx.x * 256 + threadIdx.x;
    const float e = 0.99f * old_cs[k] + 0.01f * (float)counts[k];
    out4[k] = e;
    __shared__ double red[256];
    red[threadIdx.x] = (double)e;
    __syncthreads();
    for (int s = 128; s > 0; s >>= 1) {
        if (threadIdx.x < s) red[threadIdx.x] += red[threadIdx.x + s];
        __syncthreads();
    }
    if (threadIdx.x == 0) cspart[blockIdx.x] = red[0];
}

// -------------------- ema_es + new_weight --------------------------------
__global__ __launch_bounds__(256) void k_final(
    const float* __restrict__ old_es, const float* __restrict__ sums,
    const float* __restrict__ out4, const double* __restrict__ cspart,
    float* __restrict__ out3, float* __restrict__ out5) {
    double nd = 0.0;
#pragma unroll
    for (int i = 0; i < 16; ++i) nd += cspart[i];
    const float nf = (float)nd;
    const int gid = blockIdx.x * 256 + threadIdx.x;
    const int k = gid >> 6;
    const float es = 0.99f * old_es[gid] + 0.01f * sums[gid];
    out5[gid] = es;
    const float cs = out4[k];
    const float cssm = (cs + 1e-5f) / (nf + 4096.0f * 1e-5f) * nf;
    out3[gid] = es / cssm;
}

extern "C" void kernel_launch(void* const* d_in, const int* in_sizes, int n_in,
                              void* d_out, int out_size, void* d_ws, size_t ws_size,
                              hipStream_t stream) {
    const float* x      = (const float*)d_in[0];
    const float* w      = (const float*)d_in[1];
    const float* old_cs = (const float*)d_in[2];
    const float* old_es = (const float*)d_in[3];

    float* o    = (float*)d_out;
    float* out0 = o + OUT0_OFF;
    float* out1 = o + OUT1_OFF;
    float* out2 = o + OUT2_OFF;
    float* out3 = o + OUT3_OFF;
    float* out4 = o + OUT4_OFF;
    float* out5 = o + OUT5_OFF;

    char* ws = (char*)d_ws;
    float*          bnorm  = (float*)(ws + WS_BNORM);
    int*            counts = (int*)(ws + WS_COUNTS);
    int*            candc  = (int*)(ws + WS_CANDC);
    unsigned short* cands  = (unsigned short*)(ws + WS_CANDS);
    float*          sums   = (float*)(ws + WS_SUMS);
    short*          wbf    = (short*)(ws + WS_WBF);
    double*         lpart  = (double*)(ws + WS_LPART);
    double*         cspart = (double*)(ws + WS_CSPART);

    hipMemsetAsync(counts, 0, K_CODES * sizeof(int), stream);

    k_bnorm<<<K_CODES / 256, 256, 0, stream>>>(w, bnorm);
    k_wcvtbf<<<K_CODES * D_DIM / 256, 256, 0, stream>>>(w, wbf);
    k_approx<<<N_VEC / 64, 256, 0, stream>>>(x, wbf, bnorm, candc, cands);
    k_rescore<<<N_VEC / 256, 256, 0, stream>>>(x, w, bnorm, candc, cands, out2);
    // sums overlays cands: memset only after rescore is enqueued
    hipMemsetAsync(sums, 0, K_CODES * D_DIM * sizeof(float), stream);
    k_quant<<<NELEM / 256, 256, 0, stream>>>(x, w, out2, out0, sums, counts, lpart);
    k_loss<<<1, 256, 0, stream>>>(lpart, out1);
    k_emacs<<<K_CODES / 256, 256, 0, stream>>>(old_cs, counts, out4, cspart);
    k_final<<<K_CODES * D_DIM / 256, 256, 0, stream>>>(old_es, sums, out4, cspart,
                                                       out3, out5);
}

// Round 11
// 166.838 us; speedup vs baseline: 7.1279x; 1.0066x over previous
//
#include <hip/hip_runtime.h>

#define N_VEC   32768      // 32*1024
#define K_CODES 4096
#define D_DIM   64
#define NELEM   2097152    // N_VEC * D_DIM
#define TH_APPROX 7.5e-4f

// ---- output layout (floats, concatenated in reference return order) ----
#define OUT0_OFF 0           // quantized_st  (2097152)
#define OUT1_OFF 2097152     // loss          (1)
#define OUT2_OFF 2097153     // indices       (32768)
#define OUT3_OFF 2129921     // new_weight    (262144)
#define OUT4_OFF 2392065     // ema_cs        (4096)
#define OUT5_OFF 2396161     // ema_es        (262144)

// ---- ws layout (byte offsets). Overlays are stream-ordered safe:
//  CANDS (collect/rescore) overlays SUMS (k_quant, memset AFTER rescore)
//  WBF (min/collect) overlays LPART/CSPART (k_quant/k_emacs, written later)
#define WS_BNORM   0            // float[4096]
#define WS_COUNTS  16384        // int[4096]
#define WS_CANDC   32768        // int[32768]
#define WS_CANDS   163840       // ushort[32768*16]  (1048576 B)
#define WS_SUMS    163840       // float[262144]     (1048576 B) overlay
#define WS_WBF     1212416      // short[262144]     (524288 B)
#define WS_LPART   1212416      // double[8192]      overlay
#define WS_CSPART  1277952      // double[16]        overlay
#define WS_PMIN    1736704      // float[4*32768]    (524288 B)
// total footprint 2260992 B

typedef short  s16x8 __attribute__((ext_vector_type(8)));
typedef float  f32x4 __attribute__((ext_vector_type(4)));

__device__ __forceinline__ unsigned short bf16rne(float f) {
    unsigned u = __float_as_uint(f);
    unsigned r = u + 0x7fffu + ((u >> 16) & 1u);
    return (unsigned short)(r >> 16);
}

// numpy pairwise_sum base case (n=64): 8 accumulators strided by 8,
// sequential adds, fixed combine tree. sq[] must be PRE-ROUNDED squares.
__device__ __forceinline__ float np_pairwise64(const float* sq) {
    float r0 = sq[0], r1 = sq[1], r2 = sq[2], r3 = sq[3];
    float r4 = sq[4], r5 = sq[5], r6 = sq[6], r7 = sq[7];
#pragma unroll
    for (int b = 8; b < 64; b += 8) {
        r0 = __fadd_rn(r0, sq[b + 0]); r1 = __fadd_rn(r1, sq[b + 1]);
        r2 = __fadd_rn(r2, sq[b + 2]); r3 = __fadd_rn(r3, sq[b + 3]);
        r4 = __fadd_rn(r4, sq[b + 4]); r5 = __fadd_rn(r5, sq[b + 5]);
        r6 = __fadd_rn(r6, sq[b + 6]); r7 = __fadd_rn(r7, sq[b + 7]);
    }
    return __fadd_rn(__fadd_rn(__fadd_rn(r0, r1), __fadd_rn(r2, r3)),
                     __fadd_rn(__fadd_rn(r4, r5), __fadd_rn(r6, r7)));
}

// -------- B_k = np.sum(w_k*w_k) with numpy fp32 semantics ----------------
__global__ void k_bnorm(const float* __restrict__ w, float* __restrict__ bn) {
    int k = blockIdx.x * 256 + threadIdx.x;
    const float* wr = w + k * D_DIM;
    float sq[64];
#pragma unroll
    for (int i = 0; i < 64; ++i) { float v = wr[i]; sq[i] = __fmul_rn(v, v); }
    bn[k] = np_pairwise64(sq);
}

// -------- w -> bf16 ------------------------------------------------------
__global__ void k_wcvtbf(const float* __restrict__ w, short* __restrict__ wbf) {
    int gid = blockIdx.x * 256 + threadIdx.x;
    wbf[gid] = (short)bf16rne(w[gid]);
}

// ======== MFMA prefilter, split into two grids for occupancy =============
// Mapping (both kernels): rg = blockIdx&511 (64 rows), kc = blockIdx>>9
// (k-chunk of 1024). 4 waves/block; wave wid owns cols [wid*256,+256) of
// the chunk = 16 col-tiles. 2048 blocks = 8 blocks/CU (R9's k_approx was
// 512 blocks = 2 waves/SIMD, latency-bound at 21% occupancy).
// mfma_f32_16x16x32_bf16: A row=l&15, k=(l>>4)*8+e; B col=l&15; C col=l&15,
// row=(l>>4)*4+reg (m89-verified, R9-validated end-to-end).
#define XLDS_LD 72

#define STAGE_X_BF16                                                        \
    for (int i = tid; i < 64 * 16; i += 256) {                              \
        int r = i >> 4, c4 = i & 15;                                        \
        float4 v = ((const float4*)(x + (size_t)(rbase + r) * D_DIM))[c4];  \
        ushort4 b;                                                          \
        b.x = bf16rne(v.x); b.y = bf16rne(v.y);                             \
        b.z = bf16rne(v.z); b.w = bf16rne(v.w);                             \
        *(ushort4*)&xlds[r * XLDS_LD + c4 * 4] = b;                         \
    }

#define HOIST_A_FRAGS                                                       \
    s16x8 af0[4], af1[4];                                                   \
    _Pragma("unroll")                                                       \
    for (int rt = 0; rt < 4; ++rt) {                                        \
        af0[rt] = *(const s16x8*)&xlds[(rt * 16 + arow) * XLDS_LD + agrp * 8]; \
        af1[rt] = *(const s16x8*)&xlds[(rt * 16 + arow) * XLDS_LD + 32 + agrp * 8]; \
    }

// ---- pass 1: per-row min of m = bn_k - 2*C~ over this block's chunk -----
__global__ __launch_bounds__(256, 4) void k_min(
    const float* __restrict__ x, const short* __restrict__ wbf,
    const float* __restrict__ bn, float* __restrict__ pmin) {
    __shared__ short xlds[64 * XLDS_LD];
    __shared__ float wmin[4][64];

    const int tid  = threadIdx.x;
    const int lane = tid & 63;
    const int wid  = __builtin_amdgcn_readfirstlane(tid >> 6);
    const int rg   = blockIdx.x & 511;
    const int kc   = blockIdx.x >> 9;
    const int rbase = rg * 64;
    const int arow = lane & 15;
    const int agrp = lane >> 4;

    STAGE_X_BF16
    __syncthreads();
    HOIST_A_FRAGS

    const int col0 = kc * 1024 + wid * 256;

    float rm[16];
#pragma unroll
    for (int i = 0; i < 16; ++i) rm[i] = 3.4e38f;

    for (int tc = 0; tc < 16; ++tc) {
        const int mycol = col0 + tc * 16 + arow;
        s16x8 b0 = *(const s16x8*)&wbf[(size_t)mycol * D_DIM + agrp * 8];
        s16x8 b1 = *(const s16x8*)&wbf[(size_t)mycol * D_DIM + 32 + agrp * 8];
        float bnv = bn[mycol];
#pragma unroll
        for (int rt = 0; rt < 4; ++rt) {
            f32x4 c = {0.f, 0.f, 0.f, 0.f};
            c = __builtin_amdgcn_mfma_f32_16x16x32_bf16(af0[rt], b0, c, 0, 0, 0);
            c = __builtin_amdgcn_mfma_f32_16x16x32_bf16(af1[rt], b1, c, 0, 0, 0);
#pragma unroll
            for (int j = 0; j < 4; ++j) {
                float m = fmaf(-2.0f, c[j], bnv);
                rm[rt * 4 + j] = fminf(rm[rt * 4 + j], m);
            }
        }
    }

    // cross-col (lane&15) min reduce, then block reduce across waves
#pragma unroll
    for (int i = 0; i < 16; ++i) {
        float v = rm[i];
        v = fminf(v, __shfl_xor(v, 1));
        v = fminf(v, __shfl_xor(v, 2));
        v = fminf(v, __shfl_xor(v, 4));
        v = fminf(v, __shfl_xor(v, 8));
        rm[i] = v;
    }
    if (arow == 0) {
#pragma unroll
        for (int i = 0; i < 16; ++i)
            wmin[wid][(i >> 2) * 16 + agrp * 4 + (i & 3)] = rm[i];
    }
    __syncthreads();
    if (tid < 64) {
        float g = fminf(fminf(wmin[0][tid], wmin[1][tid]),
                        fminf(wmin[2][tid], wmin[3][tid]));
        pmin[kc * N_VEC + rbase + tid] = g;
    }
}

// ---- pass 2: recompute chunk, collect m <= rowmin+TH into global list ---
__global__ __launch_bounds__(256, 4) void k_collect(
    const float* __restrict__ x, const short* __restrict__ wbf,
    const float* __restrict__ bn, const float* __restrict__ pmin,
    int* __restrict__ candc, unsigned short* __restrict__ cands) {
    __shared__ short xlds[64 * XLDS_LD];
    __shared__ float gmin[64];

    const int tid  = threadIdx.x;
    const int lane = tid & 63;
    const int wid  = __builtin_amdgcn_readfirstlane(tid >> 6);
    const int rg   = blockIdx.x & 511;
    const int kc   = blockIdx.x >> 9;
    const int rbase = rg * 64;
    const int arow = lane & 15;
    const int agrp = lane >> 4;

    STAGE_X_BF16
    if (tid < 64) {
        const int n = rbase + tid;
        float g = fminf(fminf(pmin[n], pmin[N_VEC + n]),
                        fminf(pmin[2 * N_VEC + n], pmin[3 * N_VEC + n]));
        gmin[tid] = g + TH_APPROX;
    }
    __syncthreads();
    HOIST_A_FRAGS

    float gv[16];
#pragma unroll
    for (int i = 0; i < 16; ++i)
        gv[i] = gmin[(i >> 2) * 16 + agrp * 4 + (i & 3)];

    const int col0 = kc * 1024 + wid * 256;

    for (int tc = 0; tc < 16; ++tc) {
        const int mycol = col0 + tc * 16 + arow;
        s16x8 b0 = *(const s16x8*)&wbf[(size_t)mycol * D_DIM + agrp * 8];
        s16x8 b1 = *(const s16x8*)&wbf[(size_t)mycol * D_DIM + 32 + agrp * 8];
        float bnv = bn[mycol];
#pragma unroll
        for (int rt = 0; rt < 4; ++rt) {
            f32x4 c = {0.f, 0.f, 0.f, 0.f};
            c = __builtin_amdgcn_mfma_f32_16x16x32_bf16(af0[rt], b0, c, 0, 0, 0);
            c = __builtin_amdgcn_mfma_f32_16x16x32_bf16(af1[rt], b1, c, 0, 0, 0);
#pragma unroll
            for (int j = 0; j < 4; ++j) {
                float m = fmaf(-2.0f, c[j], bnv);
                if (m <= gv[rt * 4 + j]) {
                    int n = rbase + rt * 16 + agrp * 4 + j;
                    int p = atomicAdd(&candc[n], 1);
                    if (p < 16)
                        cands[(size_t)n * 16 + p] = (unsigned short)mycol;
                }
            }
        }
    }
}

// -------- exact np rescore of the shortlist ------------------------------
__global__ __launch_bounds__(256) void k_rescore(
    const float* __restrict__ x, const float* __restrict__ w,
    const float* __restrict__ bn, const int* __restrict__ candc,
    const unsigned short* __restrict__ cands, float* __restrict__ out_idx) {
    const int n = blockIdx.x * 256 + threadIdx.x;

    float4 xv[16];
    const float4* xr = (const float4*)(x + (size_t)n * D_DIM);
#pragma unroll
    for (int i = 0; i < 16; ++i) xv[i] = xr[i];

    // A_n: numpy-exact sum of pre-rounded squares
    float A;
    {
        float sq[64];
#pragma unroll
        for (int i = 0; i < 16; ++i) {
            sq[4*i+0] = __fmul_rn(xv[i].x, xv[i].x);
            sq[4*i+1] = __fmul_rn(xv[i].y, xv[i].y);
            sq[4*i+2] = __fmul_rn(xv[i].z, xv[i].z);
            sq[4*i+3] = __fmul_rn(xv[i].w, xv[i].w);
        }
        A = np_pairwise64(sq);
    }

    const int cnt = candc[n];
    float bestd = 3.4e38f;
    int   besti = 0;

    if (cnt <= 16) {
        unsigned short cl[16];
        for (int i = 0; i < cnt; ++i) cl[i] = cands[(size_t)n * 16 + i];
        // sort ascending so strict < reproduces np first-min tie-break
        for (int i = 1; i < cnt; ++i) {
            unsigned short v = cl[i];
            int j = i - 1;
            while (j >= 0 && cl[j] > v) { cl[j + 1] = cl[j]; --j; }
            cl[j + 1] = v;
        }
        for (int i = 0; i < cnt; ++i) {
            const int c = cl[i];
            const float4* wr = (const float4*)(w + (size_t)c * D_DIM);
            float a = 0.f;
#pragma unroll
            for (int ch = 0; ch < 16; ++ch) {
                float4 u = wr[ch];
                a = __fmaf_rn(xv[ch].x, u.x, a);
                a = __fmaf_rn(xv[ch].y, u.y, a);
                a = __fmaf_rn(xv[ch].z, u.z, a);
                a = __fmaf_rn(xv[ch].w, u.w, a);
            }
            float d = __fsub_rn(__fadd_rn(A, bn[c]), __fmul_rn(2.0f, a));
            if (d < bestd) { bestd = d; besti = c; }
        }
    } else {
        // overflow fallback: full exact np scan (P ~ 0)
        for (int c = 0; c < K_CODES; ++c) {
            const float4* wr = (const float4*)(w + (size_t)c * D_DIM);
            float a = 0.f;
#pragma unroll
            for (int ch = 0; ch < 16; ++ch) {
                float4 u = wr[ch];
                a = __fmaf_rn(xv[ch].x, u.x, a);
                a = __fmaf_rn(xv[ch].y, u.y, a);
                a = __fmaf_rn(xv[ch].z, u.z, a);
                a = __fmaf_rn(xv[ch].w, u.w, a);
            }
            float d = __fsub_rn(__fadd_rn(A, bn[c]), __fmul_rn(2.0f, a));
            if (d < bestd) { bestd = d; besti = c; }
        }
    }
    out_idx[n] = (float)besti;
}

// -------------------- gather + STE output + loss partials + segment sums -
__global__ __launch_bounds__(256) void k_quant(
    const float* __restrict__ x, const float* __restrict__ w,
    const float* __restrict__ idxf, float* __restrict__ out0,
    float* __restrict__ sums, int* __restrict__ counts,
    double* __restrict__ lpart) {
    const int gid = blockIdx.x * 256 + threadIdx.x;
    const int n = gid >> 6, d = gid & 63;
    const int idx = (int)idxf[n];
    const float in = x[gid];
    const float q  = w[idx * D_DIM + d];
    out0[gid] = in + (q - in);               // straight-through
    const float diff = in - q;
    atomicAdd(&sums[idx * D_DIM + d], in);
    if (d == 0) atomicAdd(&counts[idx], 1);

    __shared__ double red[256];
    red[threadIdx.x] = (double)diff * (double)diff;
    __syncthreads();
    for (int s = 128; s > 0; s >>= 1) {
        if (threadIdx.x < s) red[threadIdx.x] += red[threadIdx.x + s];
        __syncthreads();
    }
    if (threadIdx.x == 0) lpart[blockIdx.x] = red[0];
}

// -------------------- loss finalize (deterministic) ----------------------
__global__ void k_loss(const double* __restrict__ lpart, float* __restrict__ out1) {
    __shared__ double red[256];
    double s = 0.0;
    for (int i = threadIdx.x; i < 8192; i += 256) s += lpart[i];
    red[threadIdx.x] = s;
    __syncthreads();
    for (int st = 128; st > 0; st >>= 1) {
        if (threadIdx.x < st) red[threadIdx.x] += red[threadIdx.x + st];
        __syncthreads();
    }
    if (threadIdx.x == 0) out1[0] = (float)(0.25 * red[0] / (double)NELEM);
}

// -------------------- ema_cs + partial sums for n ------------------------
__global__ void k_emacs(const float* __restrict__ old_cs, const int* __restrict__ counts,
                        float* __restrict__ out4, double* __restrict__ cspart) {
    const int k = blockIdx.x * 256 + threadIdx.x;
    const float e = 0.99f * old_cs[k] + 0.01f * (float)counts[k];
    out4[k] = e;
    __shared__ double red[256];
    red[threadIdx.x] = (double)e;
    __syncthreads();
    for (int s = 128; s > 0; s >>= 1) {
        if (threadIdx.x < s) red[threadIdx.x] += red[threadIdx.x + s];
        __syncthreads();
    }
    if (threadIdx.x == 0) cspart[blockIdx.x] = red[0];
}

// -------------------- ema_es + new_weight --------------------------------
__global__ __launch_bounds__(256) void k_final(
    const float* __restrict__ old_es, const float* __restrict__ sums,
    const float* __restrict__ out4, const double* __restrict__ cspart,
    float* __restrict__ out3, float* __restrict__ out5) {
    double nd = 0.0;
#pragma unroll
    for (int i = 0; i < 16; ++i) nd += cspart[i];
    const float nf = (float)nd;
    const int gid = blockIdx.x * 256 + threadIdx.x;
    const int k = gid >> 6;
    const float es = 0.99f * old_es[gid] + 0.01f * sums[gid];
    out5[gid] = es;
    const float cs = out4[k];
    const float cssm = (cs + 1e-5f) / (nf + 4096.0f * 1e-5f) * nf;
    out3[gid] = es / cssm;
}

extern "C" void kernel_launch(void* const* d_in, const int* in_sizes, int n_in,
                              void* d_out, int out_size, void* d_ws, size_t ws_size,
                              hipStream_t stream) {
    const float* x      = (const float*)d_in[0];
    const float* w      = (const float*)d_in[1];
    const float* old_cs = (const float*)d_in[2];
    const float* old_es = (const float*)d_in[3];

    float* o    = (float*)d_out;
    float* out0 = o + OUT0_OFF;
    float* out1 = o + OUT1_OFF;
    float* out2 = o + OUT2_OFF;
    float* out3 = o + OUT3_OFF;
    float* out4 = o + OUT4_OFF;
    float* out5 = o + OUT5_OFF;

    char* ws = (char*)d_ws;
    float*          bnorm  = (float*)(ws + WS_BNORM);
    int*            counts = (int*)(ws + WS_COUNTS);
    int*            candc  = (int*)(ws + WS_CANDC);
    unsigned short* cands  = (unsigned short*)(ws + WS_CANDS);
    float*          sums   = (float*)(ws + WS_SUMS);
    short*          wbf    = (short*)(ws + WS_WBF);
    double*         lpart  = (double*)(ws + WS_LPART);
    double*         cspart = (double*)(ws + WS_CSPART);
    float*          pmin   = (float*)(ws + WS_PMIN);

    hipMemsetAsync(counts, 0, K_CODES * sizeof(int), stream);
    hipMemsetAsync(candc, 0, N_VEC * sizeof(int), stream);

    k_bnorm<<<K_CODES / 256, 256, 0, stream>>>(w, bnorm);
    k_wcvtbf<<<K_CODES * D_DIM / 256, 256, 0, stream>>>(w, wbf);
    k_min<<<2048, 256, 0, stream>>>(x, wbf, bnorm, pmin);
    k_collect<<<2048, 256, 0, stream>>>(x, wbf, bnorm, pmin, candc, cands);
    k_rescore<<<N_VEC / 256, 256, 0, stream>>>(x, w, bnorm, candc, cands, out2);
    // sums overlays cands: memset only after rescore is enqueued
    hipMemsetAsync(sums, 0, K_CODES * D_DIM * sizeof(float), stream);
    k_quant<<<NELEM / 256, 256, 0, stream>>>(x, w, out2, out0, sums, counts, lpart);
    k_loss<<<1, 256, 0, stream>>>(lpart, out1);
    k_emacs<<<K_CODES / 256, 256, 0, stream>>>(old_cs, counts, out4, cspart);
    k_final<<<K_CODES * D_DIM / 256, 256, 0, stream>>>(old_es, sums, out4, cspart,
                                                       out3, out5);
}